// Round 3
// baseline (195.314 us; speedup 1.0000x reference)
//
#include <hip/hip_runtime.h>

// Problem shape (fixed by the reference): B=32, T=4096, E=256.
#define NROWS 32
#define TLEN  4096
#define EDIM  256
#define PER   (TLEN / 256)      // tokens per thread in the scan = 16
#define SEGS_PER_BLOCK 4        // one segment per wave, 4 waves/block

typedef float f32x4 __attribute__((ext_vector_type(4)));

// ---------------------------------------------------------------------------
// Kernel A: one block per row. Scan batch_x, write cut positions + ncuts to
// the workspace (and the fp32 ncuts tail of d_out). Runs once per iteration;
// 32 blocks, ~3 us. This removes the redundant scan from all 2048 pool
// blocks, freeing them of LDS, barriers, and scan register pressure.
// ---------------------------------------------------------------------------
__global__ __launch_bounds__(256) void scan_kernel(
    const int* __restrict__ batch_x,
    int*  __restrict__ ws_n,        // [B]
    int*  __restrict__ ws_cuts,     // [B][TLEN]
    float* __restrict__ n_cuts_out) // [B] fp32 tail of d_out
{
    const int tid  = threadIdx.x;
    const int lane = tid & 63;
    const int w    = tid >> 6;
    const int b    = blockIdx.x;

    __shared__ int s_wsum[4];

    const int* row = batch_x + (long long)b * TLEN;
    const int t0 = tid * PER;

    // pack the 16 flags into a bitmask
    unsigned mask = 0;
#pragma unroll
    for (int j = 0; j < PER; j += 4) {
        const int4 v = *(const int4*)(row + t0 + j);   // 64B-aligned
        mask |= (unsigned)(v.x == 1) << (j + 0);
        mask |= (unsigned)(v.y == 1) << (j + 1);
        mask |= (unsigned)(v.z == 1) << (j + 2);
        mask |= (unsigned)(v.w == 1) << (j + 3);
    }
    const int local = __popc(mask);

    // wave inclusive prefix (6 shuffle steps)
    int incl = local;
#pragma unroll
    for (int d = 1; d < 64; d <<= 1) {
        const int v = __shfl_up(incl, d, 64);
        if (lane >= d) incl += v;
    }
    if (lane == 63) s_wsum[w] = incl;
    __syncthreads();
    const int s0 = s_wsum[0], s1 = s_wsum[1], s2 = s_wsum[2], s3 = s_wsum[3];
    const int wbase = (w > 0 ? s0 : 0) + (w > 1 ? s1 : 0) + (w > 2 ? s2 : 0);
    const int ncuts = s0 + s1 + s2 + s3;

    int idx = wbase + incl - local;  // exclusive prefix
    int* cuts = ws_cuts + b * TLEN;
    unsigned m = mask;
    while (m) {                       // one iteration per set flag (~1/thread)
        const int j = __ffs(m) - 1;
        m &= m - 1;
        cuts[idx++] = t0 + j;
    }
    if (tid == 0) {
        ws_n[b] = ncuts;
        n_cuts_out[b] = (float)ncuts;
    }
}

// ---------------------------------------------------------------------------
// Kernel B: pure streaming pooler. Wave w of block (b,k0) mean-pools segment
// k0+w; lane l owns features [4l,4l+4). No LDS, no barriers, no scan: cut
// boundaries come from the workspace (2 wave-uniform int loads, L2-hot).
// Two 8-deep float4 load batches keep VGPR ~50 -> 8 waves/SIMD naturally,
// 8 blocks/CU co-resident, pure HBM stream.
// ---------------------------------------------------------------------------
__global__ __launch_bounds__(256, 8) void pool_kernel(
    const float* __restrict__ nn,
    const int*  __restrict__ ws_n,
    const int*  __restrict__ ws_cuts,
    int maxlen, int nb_per_row,
    float* __restrict__ out)         // [B, maxlen, E]
{
    const int tid  = threadIdx.x;
    const int lane = tid & 63;
    const int w    = tid >> 6;
    const int blk  = blockIdx.x;
    const int b    = blk / nb_per_row;                   // nb_per_row = 64
    const int k    = (blk - b * nb_per_row) * SEGS_PER_BLOCK + w;
    if (k >= maxlen) return;

    f32x4 acc = {0.f, 0.f, 0.f, 0.f};
    const int ncuts = ws_n[b];                           // wave-uniform
    if (k < ncuts) {
        const int* cuts = ws_cuts + b * TLEN;
        const int end   = cuts[k];                       // inclusive
        const int start = (k == 0) ? 0 : (cuts[k - 1] + 1);
        const int cnt   = end - start + 1;
        const float* base = nn + ((long long)b * TLEN + start) * EDIM + lane * 4;

        if (cnt == 16) {
            // fast path: two batches of 8 independent loads (32 VGPRs live)
            f32x4 v[8];
#pragma unroll
            for (int t = 0; t < 8; ++t)
                v[t] = *(const f32x4*)(base + (long long)t * EDIM);
#pragma unroll
            for (int s = 1; s < 8; s <<= 1)
#pragma unroll
                for (int t = 0; t < 8; t += 2 * s)
                    v[t] += v[t + s];
            const f32x4 sum0 = v[0];
#pragma unroll
            for (int t = 0; t < 8; ++t)
                v[t] = *(const f32x4*)(base + (long long)(8 + t) * EDIM);
#pragma unroll
            for (int s = 1; s < 8; s <<= 1)
#pragma unroll
                for (int t = 0; t < 8; t += 2 * s)
                    v[t] += v[t + s];
            acc = (sum0 + v[0]) * (1.0f / 16.0f);
        } else {
            f32x4 a0 = {0.f, 0.f, 0.f, 0.f};
            f32x4 a1 = a0, a2 = a0, a3 = a0;
            int t = 0;
            for (; t + 4 <= cnt; t += 4) {
                a0 += *(const f32x4*)(base + (long long)(t + 0) * EDIM);
                a1 += *(const f32x4*)(base + (long long)(t + 1) * EDIM);
                a2 += *(const f32x4*)(base + (long long)(t + 2) * EDIM);
                a3 += *(const f32x4*)(base + (long long)(t + 3) * EDIM);
            }
            for (; t < cnt; ++t)
                a0 += *(const f32x4*)(base + (long long)t * EDIM);
            acc = ((a0 + a1) + (a2 + a3)) * (1.0f / (float)cnt);
        }
    }
    *((f32x4*)(out + ((long long)b * maxlen + k) * EDIM) + lane) = acc;
}

extern "C" void kernel_launch(void* const* d_in, const int* in_sizes, int n_in,
                              void* d_out, int out_size, void* d_ws, size_t ws_size,
                              hipStream_t stream) {
    const float* nn_outs = (const float*)d_in[0];
    const int*   batch_x = (const int*)d_in[1];
    float* out = (float*)d_out;

    const int B = NROWS;
    const int maxlen = (out_size - B) / (B * EDIM);      // 256
    float* n_cuts_out = out + (size_t)B * maxlen * EDIM; // tail of d_out

    // workspace layout: [B] ncuts ints, then [B][TLEN] cut positions
    int* ws_n    = (int*)d_ws;
    int* ws_cuts = ws_n + B;

    scan_kernel<<<B, 256, 0, stream>>>(batch_x, ws_n, ws_cuts, n_cuts_out);

    const int nb_per_row = (maxlen + SEGS_PER_BLOCK - 1) / SEGS_PER_BLOCK;  // 64
    const int blocks = B * nb_per_row;                                      // 2048
    pool_kernel<<<blocks, 256, 0, stream>>>(nn_outs, ws_n, ws_cuts,
                                            maxlen, nb_per_row, out);
}

// Round 5
// 191.906 us; speedup vs baseline: 1.0178x; 1.0178x over previous
//
#include <hip/hip_runtime.h>

// Problem shape (fixed by the reference): B=32, T=4096, E=256.
#define NROWS 32
#define TLEN  4096
#define EDIM  256
#define PER   (TLEN / 256)      // tokens per thread in the scan = 16
#define SEGS_PER_BLOCK 4        // one segment per wave, 4 waves/block

typedef float f32x4 __attribute__((ext_vector_type(4)));

// ---------------------------------------------------------------------------
// Fused kernel (R0 structure — beat the split-kernel variant) + speculative
// prefetch: the common input has a cut every PER tokens, so segment k is
// predicted as tokens [PER*k, PER*k+PER). All 16 segment loads are issued
// BEFORE the phase-1 scan so the scan's VALU work + barriers hide under the
// HBM stream (global loads to registers stay in flight across s_barrier).
// After the scan the prediction is verified (wave-uniform); mismatch falls
// back to the general segment loop, so correctness holds for any input.
// ---------------------------------------------------------------------------
__global__ __launch_bounds__(256) void fused_pool_kernel(
    const float* __restrict__ nn,
    const int*  __restrict__ batch_x,
    int maxlen, int nb_per_row,
    float* __restrict__ out,         // [B, maxlen, E]
    float* __restrict__ n_cuts_out)  // [B] fp32 tail of d_out
{
    const int tid  = threadIdx.x;
    const int lane = tid & 63;
    const int w    = tid >> 6;
    const int blk  = blockIdx.x;
    const int b    = blk / nb_per_row;
    const int k0   = (blk - b * nb_per_row) * SEGS_PER_BLOCK;
    const int k    = k0 + w;

    __shared__ int s_cuts[TLEN];     // worst-case T cuts
    __shared__ int s_wsum[4];

    const int* row = batch_x + (long long)b * TLEN;
    const int t0 = tid * PER;

    // ---- issue flag loads first (needed first; oldest in vmem queue) ----
    const int4 f0 = *(const int4*)(row + t0 + 0);
    const int4 f1 = *(const int4*)(row + t0 + 4);
    const int4 f2 = *(const int4*)(row + t0 + 8);
    const int4 f3 = *(const int4*)(row + t0 + 12);

    // ---- speculative prefetch of segment k = [PER*k, PER*k+PER) ----
    const int ps = PER * k;
    const bool canpred = (k < maxlen) && (ps + PER <= TLEN);
    f32x4 v[16];
    if (canpred) {
        const float* pbase = nn + ((long long)b * TLEN + ps) * EDIM + lane * 4;
#pragma unroll
        for (int t = 0; t < 16; ++t)
            v[t] = *(const f32x4*)(pbase + (long long)t * EDIM);
    }

    // ---- Phase 1: scan row b (hides under the prefetch stream) ----
    unsigned mask = 0;
    mask |= (unsigned)(f0.x == 1) << 0;  mask |= (unsigned)(f0.y == 1) << 1;
    mask |= (unsigned)(f0.z == 1) << 2;  mask |= (unsigned)(f0.w == 1) << 3;
    mask |= (unsigned)(f1.x == 1) << 4;  mask |= (unsigned)(f1.y == 1) << 5;
    mask |= (unsigned)(f1.z == 1) << 6;  mask |= (unsigned)(f1.w == 1) << 7;
    mask |= (unsigned)(f2.x == 1) << 8;  mask |= (unsigned)(f2.y == 1) << 9;
    mask |= (unsigned)(f2.z == 1) << 10; mask |= (unsigned)(f2.w == 1) << 11;
    mask |= (unsigned)(f3.x == 1) << 12; mask |= (unsigned)(f3.y == 1) << 13;
    mask |= (unsigned)(f3.z == 1) << 14; mask |= (unsigned)(f3.w == 1) << 15;
    const int local = __popc(mask);

    // wave inclusive prefix (6 shuffle steps)
    int incl = local;
#pragma unroll
    for (int d = 1; d < 64; d <<= 1) {
        const int vv = __shfl_up(incl, d, 64);
        if (lane >= d) incl += vv;
    }
    if (lane == 63) s_wsum[w] = incl;
    __syncthreads();
    const int s0 = s_wsum[0], s1 = s_wsum[1], s2 = s_wsum[2], s3 = s_wsum[3];
    const int wbase = (w > 0 ? s0 : 0) + (w > 1 ? s1 : 0) + (w > 2 ? s2 : 0);
    const int ncuts = s0 + s1 + s2 + s3;

    int idx = wbase + incl - local;  // exclusive prefix
    unsigned m = mask;
    while (m) {                       // ~1 iteration per thread for this input
        const int j = __ffs(m) - 1;
        m &= m - 1;
        s_cuts[idx++] = t0 + j;
    }
    __syncthreads();

    if (k0 == 0 && tid == 0) n_cuts_out[b] = (float)ncuts;

    // ---- Phase 2: pool segment k ----
    if (k >= maxlen) return;

    f32x4 acc = {0.f, 0.f, 0.f, 0.f};
    if (k < ncuts) {
        const int start = (k == 0) ? 0 : (s_cuts[k - 1] + 1);
        const int end   = s_cuts[k];                  // inclusive
        const int cnt   = end - start + 1;

        if (canpred && start == ps && cnt == PER) {
            // prediction correct: consume the in-flight registers
#pragma unroll
            for (int s = 1; s < 16; s <<= 1)
#pragma unroll
                for (int t = 0; t < 16; t += 2 * s)
                    v[t] += v[t + s];
            acc = v[0] * (1.0f / (float)PER);
        } else {
            // general fallback
            const float* base = nn + ((long long)b * TLEN + start) * EDIM + lane * 4;
            f32x4 a0 = {0.f, 0.f, 0.f, 0.f};
            f32x4 a1 = a0, a2 = a0, a3 = a0;
            int t = 0;
            for (; t + 4 <= cnt; t += 4) {
                a0 += *(const f32x4*)(base + (long long)(t + 0) * EDIM);
                a1 += *(const f32x4*)(base + (long long)(t + 1) * EDIM);
                a2 += *(const f32x4*)(base + (long long)(t + 2) * EDIM);
                a3 += *(const f32x4*)(base + (long long)(t + 3) * EDIM);
            }
            for (; t < cnt; ++t)
                a0 += *(const f32x4*)(base + (long long)t * EDIM);
            acc = ((a0 + a1) + (a2 + a3)) * (1.0f / (float)cnt);
        }
    }
    *((f32x4*)(out + ((long long)b * maxlen + k) * EDIM) + lane) = acc;
}

extern "C" void kernel_launch(void* const* d_in, const int* in_sizes, int n_in,
                              void* d_out, int out_size, void* d_ws, size_t ws_size,
                              hipStream_t stream) {
    const float* nn_outs = (const float*)d_in[0];
    const int*   batch_x = (const int*)d_in[1];
    float* out = (float*)d_out;

    const int B = NROWS;
    const int maxlen = (out_size - B) / (B * EDIM);      // 256
    float* n_cuts_out = out + (size_t)B * maxlen * EDIM; // tail of d_out

    const int nb_per_row = (maxlen + SEGS_PER_BLOCK - 1) / SEGS_PER_BLOCK;  // 64
    const int blocks = B * nb_per_row;                                      // 2048

    fused_pool_kernel<<<blocks, 256, 0, stream>>>(nn_outs, batch_x,
                                                  maxlen, nb_per_row,
                                                  out, n_cuts_out);
}

// Round 7
// 191.338 us; speedup vs baseline: 1.0208x; 1.0030x over previous
//
#include <hip/hip_runtime.h>

// Problem shape (fixed by the reference): B=32, T=4096, E=256.
#define NROWS 32
#define TLEN  4096
#define EDIM  256
#define PER   (TLEN / 256)      // tokens per thread in the scan = 16
#define SEGS_PER_BLOCK 4        // one segment per wave, 4 waves/block

typedef float f32x4 __attribute__((ext_vector_type(4)));

// ---------------------------------------------------------------------------
// Fused kernel + speculative prefetch, round 2.
// R5 failure mechanism: __syncthreads() lowers to "s_waitcnt vmcnt(0)
// lgkmcnt(0); s_barrier" — it DRAINED the 16 speculative global loads at
// both barriers, serializing the prefetch instead of hiding the scan.
// Fix: raw s_barrier with manual lgkmcnt-only waits (LDS visibility is all
// the scan needs). Global prefetch loads now legally stay in flight across
// both barriers and drain only at consumption (compiler vmcnt).
// ---------------------------------------------------------------------------
__global__ __launch_bounds__(256) void fused_pool_kernel(
    const float* __restrict__ nn,
    const int*  __restrict__ batch_x,
    int maxlen, int nb_per_row,
    float* __restrict__ out,         // [B, maxlen, E]
    float* __restrict__ n_cuts_out)  // [B] fp32 tail of d_out
{
    const int tid  = threadIdx.x;
    const int lane = tid & 63;
    const int w    = tid >> 6;
    const int blk  = blockIdx.x;
    const int b    = blk / nb_per_row;
    const int k0   = (blk - b * nb_per_row) * SEGS_PER_BLOCK;
    const int k    = k0 + w;

    __shared__ int s_cuts[TLEN];     // worst-case T cuts
    __shared__ int s_wsum[4];

    const int* row = batch_x + (long long)b * TLEN;
    const int t0 = tid * PER;

    // ---- issue flag loads first (oldest in vmem queue -> scan can start
    //      on vmcnt(16) while the 16 nn loads are still in flight) ----
    const int4 f0 = *(const int4*)(row + t0 + 0);
    const int4 f1 = *(const int4*)(row + t0 + 4);
    const int4 f2 = *(const int4*)(row + t0 + 8);
    const int4 f3 = *(const int4*)(row + t0 + 12);

    // ---- speculative prefetch of segment k = [PER*k, PER*k+PER) ----
    const int ps = PER * k;
    const bool canpred = (k < maxlen) && (ps + PER <= TLEN);
    f32x4 v[16];
    if (canpred) {
        const float* pbase = nn + ((long long)b * TLEN + ps) * EDIM + lane * 4;
#pragma unroll
        for (int t = 0; t < 16; ++t)
            v[t] = *(const f32x4*)(pbase + (long long)t * EDIM);
    }

    // ---- Phase 1: scan row b (now genuinely hidden under the stream) ----
    unsigned mask = 0;
    mask |= (unsigned)(f0.x == 1) << 0;  mask |= (unsigned)(f0.y == 1) << 1;
    mask |= (unsigned)(f0.z == 1) << 2;  mask |= (unsigned)(f0.w == 1) << 3;
    mask |= (unsigned)(f1.x == 1) << 4;  mask |= (unsigned)(f1.y == 1) << 5;
    mask |= (unsigned)(f1.z == 1) << 6;  mask |= (unsigned)(f1.w == 1) << 7;
    mask |= (unsigned)(f2.x == 1) << 8;  mask |= (unsigned)(f2.y == 1) << 9;
    mask |= (unsigned)(f2.z == 1) << 10; mask |= (unsigned)(f2.w == 1) << 11;
    mask |= (unsigned)(f3.x == 1) << 12; mask |= (unsigned)(f3.y == 1) << 13;
    mask |= (unsigned)(f3.z == 1) << 14; mask |= (unsigned)(f3.w == 1) << 15;
    const int local = __popc(mask);

    // wave inclusive prefix (6 shuffle steps)
    int incl = local;
#pragma unroll
    for (int d = 1; d < 64; d <<= 1) {
        const int vv = __shfl_up(incl, d, 64);
        if (lane >= d) incl += vv;
    }
    if (lane == 63) s_wsum[w] = incl;

    // barrier 1: s_wsum visibility only (LDS) — do NOT drain vmcnt
    asm volatile("s_waitcnt lgkmcnt(0)" ::: "memory");
    __builtin_amdgcn_s_barrier();
    __builtin_amdgcn_sched_barrier(0);

    const int s0 = s_wsum[0], s1 = s_wsum[1], s2 = s_wsum[2], s3 = s_wsum[3];
    const int wbase = (w > 0 ? s0 : 0) + (w > 1 ? s1 : 0) + (w > 2 ? s2 : 0);
    const int ncuts = s0 + s1 + s2 + s3;

    int idx = wbase + incl - local;  // exclusive prefix
    unsigned m = mask;
    while (m) {                       // ~1 iteration per thread for this input
        const int j = __ffs(m) - 1;
        m &= m - 1;
        s_cuts[idx++] = t0 + j;
    }

    // barrier 2: s_cuts visibility only (LDS) — prefetch still in flight
    asm volatile("s_waitcnt lgkmcnt(0)" ::: "memory");
    __builtin_amdgcn_s_barrier();
    __builtin_amdgcn_sched_barrier(0);

    if (k0 == 0 && tid == 0) n_cuts_out[b] = (float)ncuts;

    // ---- Phase 2: pool segment k ----
    if (k >= maxlen) return;

    f32x4 acc = {0.f, 0.f, 0.f, 0.f};
    if (k < ncuts) {
        const int start = (k == 0) ? 0 : (s_cuts[k - 1] + 1);
        const int end   = s_cuts[k];                  // inclusive
        const int cnt   = end - start + 1;

        if (canpred && start == ps && cnt == PER) {
            // prediction correct: consume the in-flight registers
#pragma unroll
            for (int s = 1; s < 16; s <<= 1)
#pragma unroll
                for (int t = 0; t < 16; t += 2 * s)
                    v[t] += v[t + s];
            acc = v[0] * (1.0f / (float)PER);
        } else {
            // general fallback
            const float* base = nn + ((long long)b * TLEN + start) * EDIM + lane * 4;
            f32x4 a0 = {0.f, 0.f, 0.f, 0.f};
            f32x4 a1 = a0, a2 = a0, a3 = a0;
            int t = 0;
            for (; t + 4 <= cnt; t += 4) {
                a0 += *(const f32x4*)(base + (long long)(t + 0) * EDIM);
                a1 += *(const f32x4*)(base + (long long)(t + 1) * EDIM);
                a2 += *(const f32x4*)(base + (long long)(t + 2) * EDIM);
                a3 += *(const f32x4*)(base + (long long)(t + 3) * EDIM);
            }
            for (; t < cnt; ++t)
                a0 += *(const f32x4*)(base + (long long)t * EDIM);
            acc = ((a0 + a1) + (a2 + a3)) * (1.0f / (float)cnt);
        }
    }
    *((f32x4*)(out + ((long long)b * maxlen + k) * EDIM) + lane) = acc;
}

extern "C" void kernel_launch(void* const* d_in, const int* in_sizes, int n_in,
                              void* d_out, int out_size, void* d_ws, size_t ws_size,
                              hipStream_t stream) {
    const float* nn_outs = (const float*)d_in[0];
    const int*   batch_x = (const int*)d_in[1];
    float* out = (float*)d_out;

    const int B = NROWS;
    const int maxlen = (out_size - B) / (B * EDIM);      // 256
    float* n_cuts_out = out + (size_t)B * maxlen * EDIM; // tail of d_out

    const int nb_per_row = (maxlen + SEGS_PER_BLOCK - 1) / SEGS_PER_BLOCK;  // 64
    const int blocks = B * nb_per_row;                                      // 2048

    fused_pool_kernel<<<blocks, 256, 0, stream>>>(nn_outs, batch_x,
                                                  maxlen, nb_per_row,
                                                  out, n_cuts_out);
}

// Round 11
// 182.014 us; speedup vs baseline: 1.0731x; 1.0512x over previous
//
#include <hip/hip_runtime.h>

// Problem shape (fixed by the reference): B=32, T=4096, E=256.
#define NROWS 32
#define TLEN  4096
#define EDIM  256
#define PER   (TLEN / 256)      // tokens per thread in the scan = 16
#define SEGS_PER_BLOCK 4        // one segment per wave, 4 waves/block

typedef float f32x4 __attribute__((ext_vector_type(4)));

// ---------------------------------------------------------------------------
// R8: R0 fused structure (best measured: ~34 us kernel-side) with
//  - speculative prefetch REMOVED (R5/R7 measured it at -1.5us cost),
//  - raw lgkmcnt-only barriers kept (R7 vs R5: small measured win; the scan
//    only needs LDS visibility, no vmcnt drain),
//  - NON-TEMPORAL loads for the nn stream and NT stores for out. Mechanism:
//    the harness's 512 MiB poison fill leaves L3 fully dirty; allocating
//    143 MB of nn reads forces eviction-writebacks of dirty poison lines
//    during OUR kernel's window, throttling the stream to ~4.3 TB/s. NT
//    reads bypass allocation -> dirty lines stay resident and are simply
//    overwritten in place by the next fill (no writeback ever).
// ---------------------------------------------------------------------------
__global__ __launch_bounds__(256) void fused_pool_kernel(
    const float* __restrict__ nn,
    const int*  __restrict__ batch_x,
    int maxlen, int nb_per_row,
    float* __restrict__ out,         // [B, maxlen, E]
    float* __restrict__ n_cuts_out)  // [B] fp32 tail of d_out
{
    const int tid  = threadIdx.x;
    const int lane = tid & 63;
    const int w    = tid >> 6;
    const int blk  = blockIdx.x;
    const int b    = blk / nb_per_row;
    const int k0   = (blk - b * nb_per_row) * SEGS_PER_BLOCK;
    const int k    = k0 + w;

    __shared__ int s_cuts[TLEN];     // worst-case T cuts
    __shared__ int s_wsum[4];

    const int* row = batch_x + (long long)b * TLEN;
    const int t0 = tid * PER;

    // ---- Phase 1: scan row b ----
    const int4 f0 = *(const int4*)(row + t0 + 0);
    const int4 f1 = *(const int4*)(row + t0 + 4);
    const int4 f2 = *(const int4*)(row + t0 + 8);
    const int4 f3 = *(const int4*)(row + t0 + 12);

    unsigned mask = 0;
    mask |= (unsigned)(f0.x == 1) << 0;  mask |= (unsigned)(f0.y == 1) << 1;
    mask |= (unsigned)(f0.z == 1) << 2;  mask |= (unsigned)(f0.w == 1) << 3;
    mask |= (unsigned)(f1.x == 1) << 4;  mask |= (unsigned)(f1.y == 1) << 5;
    mask |= (unsigned)(f1.z == 1) << 6;  mask |= (unsigned)(f1.w == 1) << 7;
    mask |= (unsigned)(f2.x == 1) << 8;  mask |= (unsigned)(f2.y == 1) << 9;
    mask |= (unsigned)(f2.z == 1) << 10; mask |= (unsigned)(f2.w == 1) << 11;
    mask |= (unsigned)(f3.x == 1) << 12; mask |= (unsigned)(f3.y == 1) << 13;
    mask |= (unsigned)(f3.z == 1) << 14; mask |= (unsigned)(f3.w == 1) << 15;
    const int local = __popc(mask);

    // wave inclusive prefix (6 shuffle steps)
    int incl = local;
#pragma unroll
    for (int d = 1; d < 64; d <<= 1) {
        const int vv = __shfl_up(incl, d, 64);
        if (lane >= d) incl += vv;
    }
    if (lane == 63) s_wsum[w] = incl;

    // barrier 1: s_wsum visibility only (LDS) — no vmcnt drain
    asm volatile("s_waitcnt lgkmcnt(0)" ::: "memory");
    __builtin_amdgcn_s_barrier();
    __builtin_amdgcn_sched_barrier(0);

    const int s0 = s_wsum[0], s1 = s_wsum[1], s2 = s_wsum[2], s3 = s_wsum[3];
    const int wbase = (w > 0 ? s0 : 0) + (w > 1 ? s1 : 0) + (w > 2 ? s2 : 0);
    const int ncuts = s0 + s1 + s2 + s3;

    int idx = wbase + incl - local;  // exclusive prefix
    unsigned m = mask;
    while (m) {                       // ~1 iteration per thread for this input
        const int j = __ffs(m) - 1;
        m &= m - 1;
        s_cuts[idx++] = t0 + j;
    }

    // barrier 2: s_cuts visibility only (LDS)
    asm volatile("s_waitcnt lgkmcnt(0)" ::: "memory");
    __builtin_amdgcn_s_barrier();
    __builtin_amdgcn_sched_barrier(0);

    if (k0 == 0 && tid == 0) n_cuts_out[b] = (float)ncuts;

    // ---- Phase 2: pool segment k ----
    if (k >= maxlen) return;

    f32x4 acc = {0.f, 0.f, 0.f, 0.f};
    if (k < ncuts) {
        const int start = (k == 0) ? 0 : (s_cuts[k - 1] + 1);
        const int end   = s_cuts[k];                  // inclusive
        const int cnt   = end - start + 1;
        const float* base = nn + ((long long)b * TLEN + start) * EDIM + lane * 4;

        if (cnt == 16) {
            // fast path: 16 independent NT loads in flight
            f32x4 v[16];
#pragma unroll
            for (int t = 0; t < 16; ++t)
                v[t] = __builtin_nontemporal_load((const f32x4*)(base + (long long)t * EDIM));
#pragma unroll
            for (int s = 1; s < 16; s <<= 1)
#pragma unroll
                for (int t = 0; t < 16; t += 2 * s)
                    v[t] += v[t + s];
            acc = v[0] * (1.0f / 16.0f);
        } else {
            // general fallback
            f32x4 a0 = {0.f, 0.f, 0.f, 0.f};
            f32x4 a1 = a0, a2 = a0, a3 = a0;
            int t = 0;
            for (; t + 4 <= cnt; t += 4) {
                a0 += __builtin_nontemporal_load((const f32x4*)(base + (long long)(t + 0) * EDIM));
                a1 += __builtin_nontemporal_load((const f32x4*)(base + (long long)(t + 1) * EDIM));
                a2 += __builtin_nontemporal_load((const f32x4*)(base + (long long)(t + 2) * EDIM));
                a3 += __builtin_nontemporal_load((const f32x4*)(base + (long long)(t + 3) * EDIM));
            }
            for (; t < cnt; ++t)
                a0 += __builtin_nontemporal_load((const f32x4*)(base + (long long)t * EDIM));
            acc = ((a0 + a1) + (a2 + a3)) * (1.0f / (float)cnt);
        }
    }
    __builtin_nontemporal_store(acc,
        (f32x4*)(out + ((long long)b * maxlen + k) * EDIM) + lane);
}

extern "C" void kernel_launch(void* const* d_in, const int* in_sizes, int n_in,
                              void* d_out, int out_size, void* d_ws, size_t ws_size,
                              hipStream_t stream) {
    const float* nn_outs = (const float*)d_in[0];
    const int*   batch_x = (const int*)d_in[1];
    float* out = (float*)d_out;

    const int B = NROWS;
    const int maxlen = (out_size - B) / (B * EDIM);      // 256
    float* n_cuts_out = out + (size_t)B * maxlen * EDIM; // tail of d_out

    const int nb_per_row = (maxlen + SEGS_PER_BLOCK - 1) / SEGS_PER_BLOCK;  // 64
    const int blocks = B * nb_per_row;                                      // 2048

    fused_pool_kernel<<<blocks, 256, 0, stream>>>(nn_outs, batch_x,
                                                  maxlen, nb_per_row,
                                                  out, n_cuts_out);
}